// Round 4
// baseline (69.833 us; speedup 1.0000x reference)
//
#include <hip/hip_runtime.h>

// Problem constants (from reference): B=16384, L=200, V=1000000, D=20
static constexpr int B = 16384;
static constexpr int L = 200;
static constexpr int D = 20;
static constexpr int TPL = (L + 63) / 64;  // max tokens per lane = 4

typedef float f32x4 __attribute__((ext_vector_type(4)));

// One 64-lane wave per batch row; 4 waves (256 threads) per block.
__global__ __launch_bounds__(256) void wd_pool_kernel(
    const int* __restrict__ ids,    // [B, L] int32
    const float* __restrict__ emb,  // [V, D] f32, row 0 == zeros
    float* __restrict__ out)        // [B, D] f32
{
    const int lane = threadIdx.x & 63;
    const int row  = (blockIdx.x << 2) + (threadIdx.x >> 6);

    const int* __restrict__ rid = ids + (size_t)row * L;

    // Phase 1: token ids for this lane (coalesced).
    int id[TPL];
#pragma unroll
    for (int j = 0; j < TPL; ++j) {
        const int t = lane + 64 * j;
        id[j] = (t < L) ? rid[t] : 0;  // OOB/pad -> row 0 (all-zero, cache-hot)
    }

    // Phase 2: 20 gather loads issued back-to-back via volatile asm.
    // R2/R3 showed the compiler sinks C++ loads next to consumers
    // (VGPR=36/40 => ~5 in flight); volatile asm cannot be reordered,
    // so all 20 dwordx4 loads stay hoisted => 20 outstanding per wave.
    f32x4 v[TPL][5];
#pragma unroll
    for (int j = 0; j < TPL; ++j) {
        const float* p = emb + (size_t)id[j] * D;  // 80 B row, 16 B-aligned
        asm volatile("global_load_dwordx4 %0, %1, off offset:0"  : "=v"(v[j][0]) : "v"(p));
        asm volatile("global_load_dwordx4 %0, %1, off offset:16" : "=v"(v[j][1]) : "v"(p));
        asm volatile("global_load_dwordx4 %0, %1, off offset:32" : "=v"(v[j][2]) : "v"(p));
        asm volatile("global_load_dwordx4 %0, %1, off offset:48" : "=v"(v[j][3]) : "v"(p));
        asm volatile("global_load_dwordx4 %0, %1, off offset:64" : "=v"(v[j][4]) : "v"(p));
    }

    // Wait for all gathers. The "+v" operands create a TRUE data dependency:
    // every consumer of v[][] depends on this asm's outputs, so nothing can
    // be hoisted above the waitcnt (no reliance on sched_barrier).
    asm volatile("s_waitcnt vmcnt(0)"
                 : "+v"(v[0][0]), "+v"(v[0][1]), "+v"(v[0][2]), "+v"(v[0][3]), "+v"(v[0][4]),
                   "+v"(v[1][0]), "+v"(v[1][1]), "+v"(v[1][2]), "+v"(v[1][3]), "+v"(v[1][4]),
                   "+v"(v[2][0]), "+v"(v[2][1]), "+v"(v[2][2]), "+v"(v[2][3]), "+v"(v[2][4]),
                   "+v"(v[3][0]), "+v"(v[3][1]), "+v"(v[3][2]), "+v"(v[3][3]), "+v"(v[3][4]));

    // Phase 3: keep-filter + accumulate (keep iff sum over 20 dims != 0).
    float a[D];
#pragma unroll
    for (int i = 0; i < D; ++i) a[i] = 0.0f;
    float cntf = 0.0f;

#pragma unroll
    for (int j = 0; j < TPL; ++j) {
        float s = 0.0f;
#pragma unroll
        for (int q = 0; q < 5; ++q)
            s += (v[j][q][0] + v[j][q][1]) + (v[j][q][2] + v[j][q][3]);
        const float k = (s != 0.0f) ? 1.0f : 0.0f;
#pragma unroll
        for (int q = 0; q < 5; ++q) {
#pragma unroll
            for (int e = 0; e < 4; ++e) a[4 * q + e] += v[j][q][e] * k;
        }
        cntf += k;
    }

    // Phase 4: butterfly reduction across the 64-lane wave.
#pragma unroll
    for (int off = 32; off; off >>= 1) {
#pragma unroll
        for (int i = 0; i < D; ++i) a[i] += __shfl_xor(a[i], off, 64);
        cntf += __shfl_xor(cntf, off, 64);
    }

    if (lane == 0) {
        // cnt==0 -> acc==0 -> 0/1 == 0 == reference's zeros fallback.
        const float inv = 1.0f / fmaxf(cntf, 1.0f);
        float4* __restrict__ o = (float4*)(out + (size_t)row * D);
#pragma unroll
        for (int q = 0; q < 5; ++q) {
            float4 w;
            w.x = a[4 * q + 0] * inv;
            w.y = a[4 * q + 1] * inv;
            w.z = a[4 * q + 2] * inv;
            w.w = a[4 * q + 3] * inv;
            o[q] = w;
        }
    }
}

extern "C" void kernel_launch(void* const* d_in, const int* in_sizes, int n_in,
                              void* d_out, int out_size, void* d_ws, size_t ws_size,
                              hipStream_t stream) {
    const int*   ids = (const int*)d_in[0];
    const float* emb = (const float*)d_in[1];
    float*       out = (float*)d_out;

    dim3 grid(B / 4);   // 4 rows (waves) per 256-thread block
    dim3 block(256);
    hipLaunchKernelGGL(wd_pool_kernel, grid, block, 0, stream, ids, emb, out);
}

// Round 5
// 65.138 us; speedup vs baseline: 1.0721x; 1.0721x over previous
//
#include <hip/hip_runtime.h>

// Problem constants (from reference): B=16384, L=200, V=1000000, D=20
static constexpr int B = 16384;
static constexpr int L = 200;
static constexpr int D = 20;
static constexpr int TPG = 12;               // tokens per group (5 lanes each = 60 lanes)
static constexpr int NG  = (L + TPG - 1) / TPG;  // 17 groups cover 200 tokens

typedef float f32x4 __attribute__((ext_vector_type(4)));

// One 64-lane wave per batch row; 4 waves (256 threads) per block.
// Lane mapping: slot s = lane/5 (token within group), chunk c = lane%5
// (which 16B of the 80B row). 5 lanes of a token hit the SAME 1-2 cache
// lines within one instruction -> intra-instruction coalescing cuts
// TA transactions ~3x vs lane-per-token (R1-R4 all pinned at 0.5 req/cy/CU).
__global__ __launch_bounds__(256) void wd_pool_kernel(
    const int* __restrict__ ids,    // [B, L] int32
    const float* __restrict__ emb,  // [V, D] f32, row 0 == zeros
    float* __restrict__ out)        // [B, D] f32
{
    const int lane = threadIdx.x & 63;
    const int row  = (blockIdx.x << 2) + (threadIdx.x >> 6);
    const int* __restrict__ rid = ids + (size_t)row * L;

    const int s = lane / 5;        // 0..12 (s==12 for lanes 60..63: inactive)
    const int c = lane - 5 * s;    // 0..4

    // Phase 1: coalesced id preload, 4 ints per lane.
    int idv0 = rid[lane];
    int idv1 = rid[lane + 64];
    int idv2 = rid[lane + 128];
    int idv3 = (lane + 192 < L) ? rid[lane + 192] : 0;

    // Phase 2: distribute ids to 5-lane groups via bpermute, issue all 17
    // gather loads back-to-back (volatile asm: cannot be sunk/reordered).
    f32x4 v[NG];
#pragma unroll
    for (int g = 0; g < NG; ++g) {
        const int t  = TPG * g + s;          // token index for this lane's group
        const int tl = t & 63;
        const int jlo = (TPG * g) >> 6;            // compile-time
        const int jhi = (TPG * g + TPG) >> 6;      // compile-time
        int vlo = (jlo == 0) ? idv0 : (jlo == 1) ? idv1 : (jlo == 2) ? idv2 : idv3;
        int idt = __shfl(vlo, tl, 64);
        if (jhi != jlo) {   // group straddles a 64-token boundary
            int vhi = (jhi == 1) ? idv1 : (jhi == 2) ? idv2 : idv3;
            int hi  = __shfl(vhi, tl, 64);
            idt = ((t >> 6) == jhi) ? hi : idt;
        }
        const bool tvalid = (t < L) && (lane < 60);
        idt = tvalid ? idt : 0;              // invalid -> row 0 (L1-hot, zeros)

        const float* p = emb + (size_t)idt * D + 4 * c;  // 16B chunk c of row
        asm volatile("global_load_dwordx4 %0, %1, off" : "=v"(v[g]) : "v"(p));
    }

    // Single wait; "+v" data deps stop consumers from hoisting above it.
    asm volatile("s_waitcnt vmcnt(0)"
                 : "+v"(v[0]), "+v"(v[1]), "+v"(v[2]), "+v"(v[3]), "+v"(v[4]),
                   "+v"(v[5]), "+v"(v[6]), "+v"(v[7]), "+v"(v[8]), "+v"(v[9]),
                   "+v"(v[10]), "+v"(v[11]), "+v"(v[12]), "+v"(v[13]), "+v"(v[14]),
                   "+v"(v[15]), "+v"(v[16]));

    // Phase 3: keep-filter (row sum != 0, as in reference) + accumulate.
    float a0 = 0.f, a1 = 0.f, a2 = 0.f, a3 = 0.f, cntf = 0.f;
    const int gb = 5 * s;  // group base lane
#pragma unroll
    for (int g = 0; g < NG; ++g) {
        const int t = TPG * g + s;
        const float ps = (v[g][0] + v[g][1]) + (v[g][2] + v[g][3]);
        // broadcast full-row sum to all 5 lanes of the group
        const float S = ((__shfl(ps, gb, 64) + __shfl(ps, gb + 1, 64)) +
                         (__shfl(ps, gb + 2, 64) + __shfl(ps, gb + 3, 64))) +
                        __shfl(ps, gb + 4, 64);
        const bool tvalid = (t < L) && (lane < 60);
        const float k = (S != 0.0f && tvalid) ? 1.0f : 0.0f;
        a0 += v[g][0] * k;
        a1 += v[g][1] * k;
        a2 += v[g][2] * k;
        a3 += v[g][3] * k;
        cntf += k;  // every lane of the group counts; per-c totals equal
    }

    // Phase 4: reduce over the 12 slots. Steps +30, +15, then +5 and +10:
    // lane (c) ends with the sum over slots {0..11} for chunk c.
    {
        a0 += __shfl(a0, lane + 30, 64); a1 += __shfl(a1, lane + 30, 64);
        a2 += __shfl(a2, lane + 30, 64); a3 += __shfl(a3, lane + 30, 64);
        cntf += __shfl(cntf, lane + 30, 64);

        a0 += __shfl(a0, lane + 15, 64); a1 += __shfl(a1, lane + 15, 64);
        a2 += __shfl(a2, lane + 15, 64); a3 += __shfl(a3, lane + 15, 64);
        cntf += __shfl(cntf, lane + 15, 64);

        float b0 = __shfl(a0, lane + 5, 64) + __shfl(a0, lane + 10, 64);
        float b1 = __shfl(a1, lane + 5, 64) + __shfl(a1, lane + 10, 64);
        float b2 = __shfl(a2, lane + 5, 64) + __shfl(a2, lane + 10, 64);
        float b3 = __shfl(a3, lane + 5, 64) + __shfl(a3, lane + 10, 64);
        float bc = __shfl(cntf, lane + 5, 64) + __shfl(cntf, lane + 10, 64);
        a0 += b0; a1 += b1; a2 += b2; a3 += b3; cntf += bc;
    }

    // Lanes 0..4 hold dims 4c..4c+3 totals and the full row count.
    if (lane < 5) {
        // cnt==0 -> acc==0 -> 0/1 == 0 == reference's zeros fallback.
        const float inv = 1.0f / fmaxf(cntf, 1.0f);
        float4 w;
        w.x = a0 * inv; w.y = a1 * inv; w.z = a2 * inv; w.w = a3 * inv;
        *(float4*)(out + (size_t)row * D + 4 * lane) = w;  // 5 lanes x 16B = 80B
    }
}

extern "C" void kernel_launch(void* const* d_in, const int* in_sizes, int n_in,
                              void* d_out, int out_size, void* d_ws, size_t ws_size,
                              hipStream_t stream) {
    const int*   ids = (const int*)d_in[0];
    const float* emb = (const float*)d_in[1];
    float*       out = (float*)d_out;

    dim3 grid(B / 4);   // 4 rows (waves) per 256-thread block
    dim3 block(256);
    hipLaunchKernelGGL(wd_pool_kernel, grid, block, 0, stream, ids, emb, out);
}